// Round 12
// baseline (293.324 us; speedup 1.0000x reference)
//
#include <hip/hip_runtime.h>

// ---------------------------------------------------------------------------
// AGNN: h = relu(x@W1^T+b1); 4x [ h = relu(agnn(h)) ]; out = h@W2^T+b2
// N=100000, E=1600000, IN=128, HID=OUT=64, float32 in/out.
// Between layers: xn = h/(||h||+eps) stored FP16 (128 B/row) + nrm f32.
//   p = exp2( dot(xn_i * log2e, xn_j) );  out_i = sum p * nrm_j * xn_j / sum p
// Round 12: UNBUNDLE r11. The sort+gemm1 packing REGRESSED (282.6->291.5):
//   union LDS (22 KB) + merged-kernel VGPR cut gemm1 occupancy 8->3
//   blocks/CU — cost more than the saved launch gap. Reverted to r10's
//   separate build_meta_sort + gemm1_relu.
//   KEPT from r11: W2T conflict-free staging in agnn_gemm2 (j=idx&63
//   lane-fastest -> bank=(j+c)%32, 2-way free; r10's k4-fastest map was
//   8-way, 5.8M conflict-cycles in counters).
//   Everything else = r10 (282.6 us baseline).
// ---------------------------------------------------------------------------

typedef _Float16 h2 __attribute__((ext_vector_type(2)));

union U4H { uint4 u; h2 h[4]; };
union U2H { uint2 u; h2 h[2]; };
union UHI { unsigned u; h2 h; };
union UF  { unsigned u; float f; int i; };

#define DEV_INLINE __device__ __forceinline__

DEV_INLINE h2 mkh2(float a, float b) {
    h2 r; r.x = (_Float16)a; r.y = (_Float16)b; return r;
}

// x + dpp_perm(x): 0xB1 quad_perm xor1, 0x4E quad_perm xor2,
// 0x141 row_half_mirror (i^7 == xor4 after quads uniform),
// 0x140 row_mirror (i^15 == xor8 after 8-groups uniform).
template <int CTRL>
DEV_INLINE float dpp_addf(float x) {
    UF a, b;
    a.f = x;
    b.i = __builtin_amdgcn_update_dpp(0, a.i, CTRL, 0xF, 0xF, true);
    return x + b.f;
}

// Fused rowptr(binary search) + segment-local degree counting sort.
// One 1024-thread block per 1024-node segment; emits meta = (nid,p0,p1,0).
#define PSEG 1024
__global__ __launch_bounds__(1024) void build_meta_sort(const int* __restrict__ row,
                                                        int4* __restrict__ meta,
                                                        int N, int E) {
    __shared__ int ptr_s[PSEG + 1];
    __shared__ int hist[256];
    __shared__ int tmp[256];
    const int t    = threadIdx.x;
    const int base = blockIdx.x * PSEG;
    const int end  = (base + PSEG < N) ? base + PSEG : N;
    const int cnt  = end - base;

    if (t < cnt) {
        const int target = base + t;
        int lo = 0, hi = E;
        while (lo < hi) {
            int mid = (lo + hi) >> 1;
            if (row[mid] < target) lo = mid + 1; else hi = mid;
        }
        ptr_s[t] = lo;
    }
    if (t == 0) {
        const int target = end;
        int lo = 0, hi = E;
        while (lo < hi) {
            int mid = (lo + hi) >> 1;
            if (row[mid] < target) lo = mid + 1; else hi = mid;
        }
        ptr_s[cnt] = lo;
    }
    if (t < 256) hist[t] = 0;
    __syncthreads();

    int d = -1, p0v = 0, p1v = 0;
    if (t < cnt) {
        p0v = ptr_s[t];
        p1v = ptr_s[t + 1];
        d = p1v - p0v;
        if (d > 255) d = 255;
        atomicAdd(&hist[d], 1);
    }
    __syncthreads();

    int h0 = (t < 256) ? hist[t] : 0;
    int* src = hist; int* dst = tmp;
    for (int off = 1; off < 256; off <<= 1) {
        if (t < 256) dst[t] = src[t] + (t >= off ? src[t - off] : 0);
        __syncthreads();
        int* tt = src; src = dst; dst = tt;
    }
    if (t < 256) src[t] -= h0;
    __syncthreads();

    if (t < cnt) {
        int pos = base + atomicAdd(&src[d], 1);
        meta[pos] = make_int4(base + t, p0v, p1v, 0);
    }
}

#define GEMM_BODY4(w4, xv)                                      \
    acc[0].x = fmaf(xv.x, w4.x, acc[0].x);                      \
    acc[0].y = fmaf(xv.x, w4.y, acc[0].y);                      \
    acc[0].z = fmaf(xv.x, w4.z, acc[0].z);                      \
    acc[0].w = fmaf(xv.x, w4.w, acc[0].w);                      \
    acc[1].x = fmaf(xv.y, w4.x, acc[1].x);                      \
    acc[1].y = fmaf(xv.y, w4.y, acc[1].y);                      \
    acc[1].z = fmaf(xv.y, w4.z, acc[1].z);                      \
    acc[1].w = fmaf(xv.y, w4.w, acc[1].w);                      \
    acc[2].x = fmaf(xv.z, w4.x, acc[2].x);                      \
    acc[2].y = fmaf(xv.z, w4.y, acc[2].y);                      \
    acc[2].z = fmaf(xv.z, w4.z, acc[2].z);                      \
    acc[2].w = fmaf(xv.z, w4.w, acc[2].w);                      \
    acc[3].x = fmaf(xv.w, w4.x, acc[3].x);                      \
    acc[3].y = fmaf(xv.w, w4.y, acc[3].y);                      \
    acc[3].z = fmaf(xv.w, w4.z, acc[3].z);                      \
    acc[3].w = fmaf(xv.w, w4.w, acc[3].w);

// r = relu(x[i,:128]@W1^T + b1); xn[i]=f16(r/(||r||+eps)); nrm[i]=||r||+eps
// 256 threads, tile 64 nodes x 64 outs, thread = 4 nodes x 4 outs.
__global__ __launch_bounds__(256) void gemm1_relu(const float* __restrict__ x,
                                                  const float* __restrict__ W1,
                                                  const float* __restrict__ b1,
                                                  unsigned short* __restrict__ xn,
                                                  float* __restrict__ nrm,
                                                  int N) {
    __shared__ __align__(16) float Wt[32 * 64];   // 8 KiB
    __shared__ __align__(16) float xT[32 * 64];   // 8 KiB
    const int tid  = threadIdx.x;
    const int tx   = tid & 15;
    const int ty   = tid >> 4;
    const int base = blockIdx.x * 64;

    const float4* W4  = (const float4*)W1;
    const float4* x4p = (const float4*)x;

    const int wO  = tid & 63;
    const int wK4 = tid >> 6;          // [0,4)
    const int nodeA = base + wO;
    const bool okA  = nodeA < N;

    float4 wv0, wv1, xv0, xv1;
    wv0 = W4[wO * 32 + wK4];
    wv1 = W4[wO * 32 + 4 + wK4];
    xv0 = make_float4(0.f, 0.f, 0.f, 0.f);
    xv1 = xv0;
    if (okA) {
        xv0 = x4p[(size_t)nodeA * 32 + wK4];
        xv1 = x4p[(size_t)nodeA * 32 + 4 + wK4];
    }

    float4 b4 = ((const float4*)b1)[tx];
    float4 acc[4];
    acc[0] = b4; acc[1] = b4; acc[2] = b4; acc[3] = b4;

    for (int c = 0; c < 4; ++c) {
        Wt[(4 * wK4 + 0) * 64 + wO] = wv0.x;
        Wt[(4 * wK4 + 1) * 64 + wO] = wv0.y;
        Wt[(4 * wK4 + 2) * 64 + wO] = wv0.z;
        Wt[(4 * wK4 + 3) * 64 + wO] = wv0.w;
        Wt[(4 * (wK4 + 4) + 0) * 64 + wO] = wv1.x;
        Wt[(4 * (wK4 + 4) + 1) * 64 + wO] = wv1.y;
        Wt[(4 * (wK4 + 4) + 2) * 64 + wO] = wv1.z;
        Wt[(4 * (wK4 + 4) + 3) * 64 + wO] = wv1.w;
        xT[(4 * wK4 + 0) * 64 + wO] = xv0.x;
        xT[(4 * wK4 + 1) * 64 + wO] = xv0.y;
        xT[(4 * wK4 + 2) * 64 + wO] = xv0.z;
        xT[(4 * wK4 + 3) * 64 + wO] = xv0.w;
        xT[(4 * (wK4 + 4) + 0) * 64 + wO] = xv1.x;
        xT[(4 * (wK4 + 4) + 1) * 64 + wO] = xv1.y;
        xT[(4 * (wK4 + 4) + 2) * 64 + wO] = xv1.z;
        xT[(4 * (wK4 + 4) + 3) * 64 + wO] = xv1.w;
        __syncthreads();

        if (c < 3) {
            const int ko = (c + 1) * 8;
            wv0 = W4[wO * 32 + ko + wK4];
            wv1 = W4[wO * 32 + ko + 4 + wK4];
            if (okA) {
                xv0 = x4p[(size_t)nodeA * 32 + ko + wK4];
                xv1 = x4p[(size_t)nodeA * 32 + ko + 4 + wK4];
            }
        }

#pragma unroll 4
        for (int k = 0; k < 32; ++k) {
            const float4 w4 = *(const float4*)&Wt[k * 64 + 4 * tx];
            const float4 xv = *(const float4*)&xT[k * 64 + 4 * ty];
            GEMM_BODY4(w4, xv)
        }
        if (c < 3) __syncthreads();
    }

#pragma unroll
    for (int mm = 0; mm < 4; ++mm) {
        float4 r = acc[mm];
        r.x = fmaxf(r.x, 0.f); r.y = fmaxf(r.y, 0.f);
        r.z = fmaxf(r.z, 0.f); r.w = fmaxf(r.w, 0.f);
        float s = fmaf(r.x, r.x, fmaf(r.y, r.y, fmaf(r.z, r.z, r.w * r.w)));
        s = dpp_addf<0xB1>(s);
        s = dpp_addf<0x4E>(s);
        s = dpp_addf<0x141>(s);
        s = dpp_addf<0x140>(s);
        const float nn  = sqrtf(s) + 1e-12f;
        const float inv = 1.f / nn;
        int node = base + 4 * ty + mm;
        if (node < N) {
            U2H pk;
            pk.h[0] = mkh2(r.x * inv, r.y * inv);
            pk.h[1] = mkh2(r.z * inv, r.w * inv);
            *(uint2*)&xn[(size_t)node * 64 + 4 * tx] = pk.u;
            if (tx == mm) nrm[node] = nn;
        }
    }
}

// Shared agnn edge-loop body (r7 burst-gather).
#define AGNN_EDGE_LOOP()                                                     \
    for (; t < e_; t += 8) {                                                 \
        const int nb = e_ - t;                                               \
        int   jj[8];                                                         \
        uint4 v[8];                                                          \
        float nm[8];                                                         \
        _Pragma("unroll")                                                    \
        for (int k = 0; k < 8; ++k) {                                        \
            int e = t + k;                                                   \
            e = (e < e_) ? e : (e_ - 1);                                     \
            jj[k] = col[e];                                                  \
        }                                                                    \
        _Pragma("unroll")                                                    \
        for (int k = 0; k < 8; ++k) v[k] = xn4[(unsigned)jj[k] * 8u + sub];  \
        _Pragma("unroll")                                                    \
        for (int k = 0; k < 8; ++k) nm[k] = nrm[jj[k]];                      \
        _Pragma("unroll")                                                    \
        for (int k = 0; k < 8; ++k) {                                        \
            U4H xa; xa.u = v[k];                                             \
            float sa = __builtin_amdgcn_fdot2(hi_.h[0], xa.h[0], 0.f, false);\
            sa = __builtin_amdgcn_fdot2(hi_.h[1], xa.h[1], sa, false);       \
            float sb = __builtin_amdgcn_fdot2(hi_.h[2], xa.h[2], 0.f, false);\
            sb = __builtin_amdgcn_fdot2(hi_.h[3], xa.h[3], sb, false);       \
            float s = sa + sb;                                               \
            s = dpp_addf<0xB1>(s);                                           \
            s = dpp_addf<0x4E>(s);                                           \
            s = dpp_addf<0x141>(s);                                          \
            const float p = (k < nb) ? exp2f(s) : 0.f;                       \
            den += p;                                                        \
            const _Float16 wh = (_Float16)(p * nm[k]);                       \
            h2 w2 = {wh, wh};                                                \
            acc.h[0] += w2 * xa.h[0];                                        \
            acc.h[1] += w2 * xa.h[1];                                        \
            acc.h[2] += w2 * xa.h[2];                                        \
            acc.h[3] += w2 * xa.h[3];                                        \
        }                                                                    \
    }

// Plain agnn (layers 1-3): writes xn + nrm for the next layer.
__global__ __launch_bounds__(256, 6) void agnn_layer(const uint4* __restrict__ xn4,
                                                     const float* __restrict__ nrm,
                                                     const int4* __restrict__ meta,
                                                     const int* __restrict__ col,
                                                     uint4* __restrict__ xo4,
                                                     float* __restrict__ nrmo,
                                                     int N) {
    const int tid  = threadIdx.x;
    const int lane = tid & 63;
    const int g    = (lane >> 3) & 1;
    const int sub  = lane & 7;
    const int slot = blockIdx.x * 16 + (tid >> 4);
    if (slot >= N) return;

    const int4 m0 = meta[slot];
    const int i  = m0.x;
    const int p0 = m0.y, p1 = m0.z;

    U4H hi_;
    hi_.u = xn4[(unsigned)i * 8u + sub];
    {
        const _Float16 L2E = (_Float16)1.4426950408889634f;
        h2 l2 = {L2E, L2E};
#pragma unroll
        for (int c = 0; c < 4; ++c) hi_.h[c] *= l2;
    }

    const int mid = p0 + ((p1 - p0 + 1) >> 1);
    int       t   = g ? mid : p0;
    const int e_  = g ? p1  : mid;

    float den = 0.f;
    U4H acc;
    acc.h[0] = mkh2(0.f, 0.f); acc.h[1] = mkh2(0.f, 0.f);
    acc.h[2] = mkh2(0.f, 0.f); acc.h[3] = mkh2(0.f, 0.f);

    AGNN_EDGE_LOOP()

    den = dpp_addf<0x140>(den);
#pragma unroll
    for (int c = 0; c < 4; ++c) {
        UHI a; a.h = acc.h[c];
        UHI b; b.u = (unsigned)__shfl_xor((int)a.u, 8, 64);
        acc.h[c] = a.h + b.h;
    }

    const float id = 1.f / fmaxf(den, 1e-12f);
    float o[8];
#pragma unroll
    for (int c = 0; c < 4; ++c) {
        o[2 * c]     = fmaxf((float)acc.h[c].x * id, 0.f);
        o[2 * c + 1] = fmaxf((float)acc.h[c].y * id, 0.f);
    }

    float s2 = 0.f;
#pragma unroll
    for (int c = 0; c < 8; ++c) s2 = fmaf(o[c], o[c], s2);
    s2 = dpp_addf<0xB1>(s2);
    s2 = dpp_addf<0x4E>(s2);
    s2 = dpp_addf<0x141>(s2);
    const float nn  = sqrtf(s2) + 1e-12f;
    const float inv = 1.f / nn;

    if (g == 0) {
        U4H ov;
        ov.h[0] = mkh2(o[0] * inv, o[1] * inv);
        ov.h[1] = mkh2(o[2] * inv, o[3] * inv);
        ov.h[2] = mkh2(o[4] * inv, o[5] * inv);
        ov.h[3] = mkh2(o[6] * inv, o[7] * inv);
        xo4[(unsigned)i * 8u + sub] = ov.u;
        if (sub == 0) nrmo[i] = nn;
    }
}

// Layer 4 + gemm2 fused: out[i,:64] = o_i @ W2^T + b2 from f32 o directly.
// W2T staged conflict-free: j (lane-consecutive) fastest -> bank=(j+c)%32,
// 2-way aliasing only (r10's k4-fastest map was 8-way, 5.8M conflict-cyc).
__global__ __launch_bounds__(256, 6) void agnn_gemm2(const uint4* __restrict__ xn4,
                                                     const float* __restrict__ nrm,
                                                     const int4* __restrict__ meta,
                                                     const int* __restrict__ col,
                                                     const float* __restrict__ W2,
                                                     const float* __restrict__ b2,
                                                     float* __restrict__ out,
                                                     int N) {
    __shared__ __align__(16) float W2T[64 * 68];   // 17 KiB, [k][j] stride 68
    __shared__ __align__(16) float oL[16][68];     // 4.25 KiB
    const int tid  = threadIdx.x;
    const int lane = tid & 63;
    const int g    = (lane >> 3) & 1;
    const int sub  = lane & 7;
    const int q    = tid >> 4;         // quarter within block [0,16)
    const int il   = tid & 15;         // lane within quarter
    const int slot = blockIdx.x * 16 + q;
    const bool slotOK = slot < N;

    // stage W2^T, conflict-free: j = idx&63 lane-fastest
    {
        const float4* src = (const float4*)W2;
#pragma unroll
        for (int i2 = 0; i2 < 4; ++i2) {
            int idx = tid + i2 * 256;            // [0,1024)
            int j = idx & 63, k4 = idx >> 6;     // k4 in [0,16)
            float4 v = src[j * 16 + k4];
            W2T[(4 * k4 + 0) * 68 + j] = v.x;
            W2T[(4 * k4 + 1) * 68 + j] = v.y;
            W2T[(4 * k4 + 2) * 68 + j] = v.z;
            W2T[(4 * k4 + 3) * 68 + j] = v.w;
        }
    }

    int nid = 0;
    if (slotOK) {
        const int4 m0 = meta[slot];
        nid = m0.x;
        const int p0 = m0.y, p1 = m0.z;
        const int i = nid;

        U4H hi_;
        hi_.u = xn4[(unsigned)i * 8u + sub];
        {
            const _Float16 L2E = (_Float16)1.4426950408889634f;
            h2 l2 = {L2E, L2E};
#pragma unroll
            for (int c = 0; c < 4; ++c) hi_.h[c] *= l2;
        }

        const int mid = p0 + ((p1 - p0 + 1) >> 1);
        int       t   = g ? mid : p0;
        const int e_  = g ? p1  : mid;

        float den = 0.f;
        U4H acc;
        acc.h[0] = mkh2(0.f, 0.f); acc.h[1] = mkh2(0.f, 0.f);
        acc.h[2] = mkh2(0.f, 0.f); acc.h[3] = mkh2(0.f, 0.f);

        AGNN_EDGE_LOOP()

        den = dpp_addf<0x140>(den);
#pragma unroll
        for (int c = 0; c < 4; ++c) {
            UHI a; a.h = acc.h[c];
            UHI b; b.u = (unsigned)__shfl_xor((int)a.u, 8, 64);
            acc.h[c] = a.h + b.h;
        }

        const float id = 1.f / fmaxf(den, 1e-12f);
        float o[8];
#pragma unroll
        for (int c = 0; c < 4; ++c) {
            o[2 * c]     = fmaxf((float)acc.h[c].x * id, 0.f);
            o[2 * c + 1] = fmaxf((float)acc.h[c].y * id, 0.f);
        }

        // stage this node's f32 o into oL (no f16 rounding)
        if (g == 0) {
            oL[q][8 * sub + 0] = o[0];
            oL[q][8 * sub + 1] = o[1];
            oL[q][8 * sub + 2] = o[2];
            oL[q][8 * sub + 3] = o[3];
            oL[q][8 * sub + 4] = o[4];
            oL[q][8 * sub + 5] = o[5];
            oL[q][8 * sub + 6] = o[6];
            oL[q][8 * sub + 7] = o[7];
        }
    }

    __syncthreads();   // W2T + oL visible to all

    if (slotOK) {
        float4 res = ((const float4*)b2)[il];
#pragma unroll 4
        for (int kk = 0; kk < 16; ++kk) {
            const float4 o4 = *(const float4*)&oL[q][4 * kk];
#pragma unroll
            for (int c = 0; c < 4; ++c) {
                const int k = 4 * kk + c;
                const float4 w4 = *(const float4*)&W2T[k * 68 + 4 * il];
                const float ok = (c == 0) ? o4.x : (c == 1) ? o4.y
                               : (c == 2) ? o4.z : o4.w;
                res.x = fmaf(ok, w4.x, res.x);
                res.y = fmaf(ok, w4.y, res.y);
                res.z = fmaf(ok, w4.z, res.z);
                res.w = fmaf(ok, w4.w, res.w);
            }
        }
        *(float4*)&out[(size_t)nid * 64 + 4 * il] = res;
    }
}

extern "C" void kernel_launch(void* const* d_in, const int* in_sizes, int n_in,
                              void* d_out, int out_size, void* d_ws, size_t ws_size,
                              hipStream_t stream) {
    const float* x   = (const float*)d_in[0];
    const int*   row = (const int*)d_in[1];
    const int*   col = (const int*)d_in[2];
    const float* W1  = (const float*)d_in[3];
    const float* b1  = (const float*)d_in[4];
    const float* W2  = (const float*)d_in[5];
    const float* b2  = (const float*)d_in[6];
    float* out = (float*)d_out;

    const int N = in_sizes[0] / 128;
    const int E = in_sizes[1];

    char* ws = (char*)d_ws;
    size_t off = 0;
    unsigned short* ha = (unsigned short*)(ws + off); off += (size_t)N * 64 * 2;
    unsigned short* hb = (unsigned short*)(ws + off); off += (size_t)N * 64 * 2;
    float* na_  = (float*)(ws + off); off += (size_t)N * sizeof(float);
    float* nb_  = (float*)(ws + off); off += (size_t)N * sizeof(float);
    off = (off + 15) & ~(size_t)15;
    int4*  meta = (int4*) (ws + off); off += (size_t)N * sizeof(int4);
    (void)ws_size; (void)n_in; (void)out_size;

    // fused rowptr(binsearch) + degree sort -> meta
    build_meta_sort<<<(N + PSEG - 1) / PSEG, 1024, 0, stream>>>(row, meta, N, E);

    const int nbG = (N + 63) / 64;
    gemm1_relu<<<nbG, 256, 0, stream>>>(x, W1, b1, ha, na_, N);

    const int nb16 = (N + 15) / 16;
    unsigned short* hc = ha; unsigned short* hn = hb;
    float* nc = na_; float* nn = nb_;
    for (int l = 0; l < 3; ++l) {
        agnn_layer<<<nb16, 256, 0, stream>>>((const uint4*)hc, nc, meta, col,
                                             (uint4*)hn, nn, N);
        unsigned short* t = hc; hc = hn; hn = t;
        float* tf = nc; nc = nn; nn = tf;
    }

    // layer 4 + gemm2 fused
    agnn_gemm2<<<nb16, 256, 0, stream>>>((const uint4*)hc, nc, meta, col,
                                         W2, b2, out, N);
}

// Round 13
// 274.909 us; speedup vs baseline: 1.0670x; 1.0670x over previous
//
#include <hip/hip_runtime.h>

// ---------------------------------------------------------------------------
// AGNN: h = relu(x@W1^T+b1); 4x [ h = relu(agnn(h)) ]; out = h@W2^T+b2
// N=100000, E=1600000, IN=128, HID=OUT=64, float32 in/out.
// Between layers: xn = h/(||h||+eps) stored FP16 (128 B/row) + nrm f32.
//   p = exp2( dot(xn_i * log2e, xn_j) );  out_i = sum p * nrm_j * xn_j / sum p
// Round 13 (r12 post-mortem):
//   - agnn_gemm2 W2T staging REVERTED to r10's coalesced-read form. r12
//     proved the 5.8M LDS store conflicts are off the critical path; the
//     "conflict-free" variant's uncoalesced W2 reads cost +6.7 us/dispatch.
//   - sort + gemm1 packed into one dispatch with OVERLAID LDS (union
//     6.2 KB sort / 16.4 KB gemm1 = 16.4 KB — r11's mistake was side-by-
//     side 22 KB, which cut gemm1 occupancy; r11-vs-r12 delta shows the
//     pack itself was ~neutral even then).
//   Everything else identical to r10 (282.6 us best).
// ---------------------------------------------------------------------------

typedef _Float16 h2 __attribute__((ext_vector_type(2)));

union U4H { uint4 u; h2 h[4]; };
union U2H { uint2 u; h2 h[2]; };
union UHI { unsigned u; h2 h; };
union UF  { unsigned u; float f; int i; };

#define DEV_INLINE __device__ __forceinline__

DEV_INLINE h2 mkh2(float a, float b) {
    h2 r; r.x = (_Float16)a; r.y = (_Float16)b; return r;
}

// x + dpp_perm(x): 0xB1 quad_perm xor1, 0x4E quad_perm xor2,
// 0x141 row_half_mirror (i^7 == xor4 after quads uniform),
// 0x140 row_mirror (i^15 == xor8 after 8-groups uniform).
template <int CTRL>
DEV_INLINE float dpp_addf(float x) {
    UF a, b;
    a.f = x;
    b.i = __builtin_amdgcn_update_dpp(0, a.i, CTRL, 0xF, 0xF, true);
    return x + b.f;
}

#define PSEG 1024

#define GEMM_BODY4(w4, xv)                                      \
    acc[0].x = fmaf(xv.x, w4.x, acc[0].x);                      \
    acc[0].y = fmaf(xv.x, w4.y, acc[0].y);                      \
    acc[0].z = fmaf(xv.x, w4.z, acc[0].z);                      \
    acc[0].w = fmaf(xv.x, w4.w, acc[0].w);                      \
    acc[1].x = fmaf(xv.y, w4.x, acc[1].x);                      \
    acc[1].y = fmaf(xv.y, w4.y, acc[1].y);                      \
    acc[1].z = fmaf(xv.y, w4.z, acc[1].z);                      \
    acc[1].w = fmaf(xv.y, w4.w, acc[1].w);                      \
    acc[2].x = fmaf(xv.z, w4.x, acc[2].x);                      \
    acc[2].y = fmaf(xv.z, w4.y, acc[2].y);                      \
    acc[2].z = fmaf(xv.z, w4.z, acc[2].z);                      \
    acc[2].w = fmaf(xv.z, w4.w, acc[2].w);                      \
    acc[3].x = fmaf(xv.w, w4.x, acc[3].x);                      \
    acc[3].y = fmaf(xv.w, w4.y, acc[3].y);                      \
    acc[3].z = fmaf(xv.w, w4.z, acc[3].z);                      \
    acc[3].w = fmaf(xv.w, w4.w, acc[3].w);

// Packed dispatch with OVERLAID LDS:
//   blocks [0,nbSort): fused rowptr(binsearch) + 256-bucket degree sort
//     (256 thr, 4 nodes/thread) -> meta = (nid,p0,p1,0).  Uses 6.2 KB.
//   blocks [nbSort,..): gemm1, 64-node x 64-out tile, 4x4/thread. 16.4 KB.
__global__ __launch_bounds__(256) void pre_gemm1(const int* __restrict__ row,
                                                 int4* __restrict__ meta,
                                                 const float* __restrict__ x,
                                                 const float* __restrict__ W1,
                                                 const float* __restrict__ b1,
                                                 unsigned short* __restrict__ xn,
                                                 float* __restrict__ nrm,
                                                 int N, int E, int nbSort) {
    __shared__ __align__(16) char smem[16384];   // overlay: max(6160, 16384)

    if ((int)blockIdx.x < nbSort) {
        // ---------------- sort path (uses first 6.2 KB of smem) ----------
        int* ptr_s = (int*)smem;                 // 1025 ints @ 0
        int* hist  = (int*)(smem + 4112);        // 256 ints
        int* tmp   = (int*)(smem + 5136);        // 256 ints  (end 6160)
        const int t    = threadIdx.x;
        const int base = blockIdx.x * PSEG;
        const int end  = (base + PSEG < N) ? base + PSEG : N;
        const int cnt  = end - base;

#pragma unroll
        for (int r = 0; r < 4; ++r) {
            const int idx = t + 256 * r;
            if (idx < cnt) {
                const int target = base + idx;
                int lo = 0, hi = E;
                while (lo < hi) {
                    int m = (lo + hi) >> 1;
                    if (row[m] < target) lo = m + 1; else hi = m;
                }
                ptr_s[idx] = lo;
            }
        }
        if (t == 0) {
            const int target = end;
            int lo = 0, hi = E;
            while (lo < hi) {
                int m = (lo + hi) >> 1;
                if (row[m] < target) lo = m + 1; else hi = m;
            }
            ptr_s[cnt] = lo;
        }
        hist[t] = 0;
        __syncthreads();

        int dv[4], p0v[4], p1v[4];
#pragma unroll
        for (int r = 0; r < 4; ++r) {
            const int idx = t + 256 * r;
            dv[r] = -1;
            if (idx < cnt) {
                p0v[r] = ptr_s[idx];
                p1v[r] = ptr_s[idx + 1];
                int d = p1v[r] - p0v[r];
                if (d > 255) d = 255;
                dv[r] = d;
                atomicAdd(&hist[d], 1);
            }
        }
        __syncthreads();

        const int h0 = hist[t];
        int* src = hist; int* dst = tmp;
        for (int off = 1; off < 256; off <<= 1) {   // 8 iters -> src==hist
            dst[t] = src[t] + (t >= off ? src[t - off] : 0);
            __syncthreads();
            int* tt = src; src = dst; dst = tt;
        }
        src[t] -= h0;
        __syncthreads();

#pragma unroll
        for (int r = 0; r < 4; ++r) {
            const int idx = t + 256 * r;
            if (idx < cnt) {
                int pos = base + atomicAdd(&src[dv[r]], 1);
                meta[pos] = make_int4(base + idx, p0v[r], p1v[r], 0);
            }
        }
        return;
    }

    // ---------------- gemm1 path (uses all 16.4 KB of smem) --------------
    float* Wt = (float*)smem;                    // 32*64 floats @ 0
    float* xT = (float*)(smem + 8192);           // 32*64 floats
    const int tid  = threadIdx.x;
    const int tx   = tid & 15;
    const int ty   = tid >> 4;
    const int base = (blockIdx.x - nbSort) * 64;

    const float4* W4  = (const float4*)W1;
    const float4* x4p = (const float4*)x;

    const int wO  = tid & 63;
    const int wK4 = tid >> 6;          // [0,4)
    const int nodeA = base + wO;
    const bool okA  = nodeA < N;

    float4 wv0, wv1, xv0, xv1;
    wv0 = W4[wO * 32 + wK4];
    wv1 = W4[wO * 32 + 4 + wK4];
    xv0 = make_float4(0.f, 0.f, 0.f, 0.f);
    xv1 = xv0;
    if (okA) {
        xv0 = x4p[(size_t)nodeA * 32 + wK4];
        xv1 = x4p[(size_t)nodeA * 32 + 4 + wK4];
    }

    float4 b4 = ((const float4*)b1)[tx];
    float4 acc[4];
    acc[0] = b4; acc[1] = b4; acc[2] = b4; acc[3] = b4;

    for (int c = 0; c < 4; ++c) {
        Wt[(4 * wK4 + 0) * 64 + wO] = wv0.x;
        Wt[(4 * wK4 + 1) * 64 + wO] = wv0.y;
        Wt[(4 * wK4 + 2) * 64 + wO] = wv0.z;
        Wt[(4 * wK4 + 3) * 64 + wO] = wv0.w;
        Wt[(4 * (wK4 + 4) + 0) * 64 + wO] = wv1.x;
        Wt[(4 * (wK4 + 4) + 1) * 64 + wO] = wv1.y;
        Wt[(4 * (wK4 + 4) + 2) * 64 + wO] = wv1.z;
        Wt[(4 * (wK4 + 4) + 3) * 64 + wO] = wv1.w;
        xT[(4 * wK4 + 0) * 64 + wO] = xv0.x;
        xT[(4 * wK4 + 1) * 64 + wO] = xv0.y;
        xT[(4 * wK4 + 2) * 64 + wO] = xv0.z;
        xT[(4 * wK4 + 3) * 64 + wO] = xv0.w;
        xT[(4 * (wK4 + 4) + 0) * 64 + wO] = xv1.x;
        xT[(4 * (wK4 + 4) + 1) * 64 + wO] = xv1.y;
        xT[(4 * (wK4 + 4) + 2) * 64 + wO] = xv1.z;
        xT[(4 * (wK4 + 4) + 3) * 64 + wO] = xv1.w;
        __syncthreads();

        if (c < 3) {
            const int ko = (c + 1) * 8;
            wv0 = W4[wO * 32 + ko + wK4];
            wv1 = W4[wO * 32 + ko + 4 + wK4];
            if (okA) {
                xv0 = x4p[(size_t)nodeA * 32 + ko + wK4];
                xv1 = x4p[(size_t)nodeA * 32 + ko + 4 + wK4];
            }
        }

#pragma unroll 4
        for (int k = 0; k < 32; ++k) {
            const float4 w4 = *(const float4*)&Wt[k * 64 + 4 * tx];
            const float4 xv = *(const float4*)&xT[k * 64 + 4 * ty];
            GEMM_BODY4(w4, xv)
        }
        if (c < 3) __syncthreads();
    }

#pragma unroll
    for (int mm = 0; mm < 4; ++mm) {
        float4 r = acc[mm];
        r.x = fmaxf(r.x, 0.f); r.y = fmaxf(r.y, 0.f);
        r.z = fmaxf(r.z, 0.f); r.w = fmaxf(r.w, 0.f);
        float s = fmaf(r.x, r.x, fmaf(r.y, r.y, fmaf(r.z, r.z, r.w * r.w)));
        s = dpp_addf<0xB1>(s);
        s = dpp_addf<0x4E>(s);
        s = dpp_addf<0x141>(s);
        s = dpp_addf<0x140>(s);
        const float nn  = sqrtf(s) + 1e-12f;
        const float inv = 1.f / nn;
        int node = base + 4 * ty + mm;
        if (node < N) {
            U2H pk;
            pk.h[0] = mkh2(r.x * inv, r.y * inv);
            pk.h[1] = mkh2(r.z * inv, r.w * inv);
            *(uint2*)&xn[(size_t)node * 64 + 4 * tx] = pk.u;
            if (tx == mm) nrm[node] = nn;
        }
    }
}

// Shared agnn edge-loop body (r7 burst-gather).
#define AGNN_EDGE_LOOP()                                                     \
    for (; t < e_; t += 8) {                                                 \
        const int nb = e_ - t;                                               \
        int   jj[8];                                                         \
        uint4 v[8];                                                          \
        float nm[8];                                                         \
        _Pragma("unroll")                                                    \
        for (int k = 0; k < 8; ++k) {                                        \
            int e = t + k;                                                   \
            e = (e < e_) ? e : (e_ - 1);                                     \
            jj[k] = col[e];                                                  \
        }                                                                    \
        _Pragma("unroll")                                                    \
        for (int k = 0; k < 8; ++k) v[k] = xn4[(unsigned)jj[k] * 8u + sub];  \
        _Pragma("unroll")                                                    \
        for (int k = 0; k < 8; ++k) nm[k] = nrm[jj[k]];                      \
        _Pragma("unroll")                                                    \
        for (int k = 0; k < 8; ++k) {                                        \
            U4H xa; xa.u = v[k];                                             \
            float sa = __builtin_amdgcn_fdot2(hi_.h[0], xa.h[0], 0.f, false);\
            sa = __builtin_amdgcn_fdot2(hi_.h[1], xa.h[1], sa, false);       \
            float sb = __builtin_amdgcn_fdot2(hi_.h[2], xa.h[2], 0.f, false);\
            sb = __builtin_amdgcn_fdot2(hi_.h[3], xa.h[3], sb, false);       \
            float s = sa + sb;                                               \
            s = dpp_addf<0xB1>(s);                                           \
            s = dpp_addf<0x4E>(s);                                           \
            s = dpp_addf<0x141>(s);                                          \
            const float p = (k < nb) ? exp2f(s) : 0.f;                       \
            den += p;                                                        \
            const _Float16 wh = (_Float16)(p * nm[k]);                       \
            h2 w2 = {wh, wh};                                                \
            acc.h[0] += w2 * xa.h[0];                                        \
            acc.h[1] += w2 * xa.h[1];                                        \
            acc.h[2] += w2 * xa.h[2];                                        \
            acc.h[3] += w2 * xa.h[3];                                        \
        }                                                                    \
    }

// Plain agnn (layers 1-3): writes xn + nrm for the next layer.
__global__ __launch_bounds__(256, 6) void agnn_layer(const uint4* __restrict__ xn4,
                                                     const float* __restrict__ nrm,
                                                     const int4* __restrict__ meta,
                                                     const int* __restrict__ col,
                                                     uint4* __restrict__ xo4,
                                                     float* __restrict__ nrmo,
                                                     int N) {
    const int tid  = threadIdx.x;
    const int lane = tid & 63;
    const int g    = (lane >> 3) & 1;
    const int sub  = lane & 7;
    const int slot = blockIdx.x * 16 + (tid >> 4);
    if (slot >= N) return;

    const int4 m0 = meta[slot];
    const int i  = m0.x;
    const int p0 = m0.y, p1 = m0.z;

    U4H hi_;
    hi_.u = xn4[(unsigned)i * 8u + sub];
    {
        const _Float16 L2E = (_Float16)1.4426950408889634f;
        h2 l2 = {L2E, L2E};
#pragma unroll
        for (int c = 0; c < 4; ++c) hi_.h[c] *= l2;
    }

    const int mid = p0 + ((p1 - p0 + 1) >> 1);
    int       t   = g ? mid : p0;
    const int e_  = g ? p1  : mid;

    float den = 0.f;
    U4H acc;
    acc.h[0] = mkh2(0.f, 0.f); acc.h[1] = mkh2(0.f, 0.f);
    acc.h[2] = mkh2(0.f, 0.f); acc.h[3] = mkh2(0.f, 0.f);

    AGNN_EDGE_LOOP()

    den = dpp_addf<0x140>(den);
#pragma unroll
    for (int c = 0; c < 4; ++c) {
        UHI a; a.h = acc.h[c];
        UHI b; b.u = (unsigned)__shfl_xor((int)a.u, 8, 64);
        acc.h[c] = a.h + b.h;
    }

    const float id = 1.f / fmaxf(den, 1e-12f);
    float o[8];
#pragma unroll
    for (int c = 0; c < 4; ++c) {
        o[2 * c]     = fmaxf((float)acc.h[c].x * id, 0.f);
        o[2 * c + 1] = fmaxf((float)acc.h[c].y * id, 0.f);
    }

    float s2 = 0.f;
#pragma unroll
    for (int c = 0; c < 8; ++c) s2 = fmaf(o[c], o[c], s2);
    s2 = dpp_addf<0xB1>(s2);
    s2 = dpp_addf<0x4E>(s2);
    s2 = dpp_addf<0x141>(s2);
    const float nn  = sqrtf(s2) + 1e-12f;
    const float inv = 1.f / nn;

    if (g == 0) {
        U4H ov;
        ov.h[0] = mkh2(o[0] * inv, o[1] * inv);
        ov.h[1] = mkh2(o[2] * inv, o[3] * inv);
        ov.h[2] = mkh2(o[4] * inv, o[5] * inv);
        ov.h[3] = mkh2(o[6] * inv, o[7] * inv);
        xo4[(unsigned)i * 8u + sub] = ov.u;
        if (sub == 0) nrmo[i] = nn;
    }
}

// Layer 4 + gemm2 fused: out[i,:64] = o_i @ W2^T + b2 from f32 o directly.
// W2T staging = r10's coalesced-read form (r12 proved its LDS store
// conflicts are off critical path; coalesced global reads matter more).
__global__ __launch_bounds__(256, 6) void agnn_gemm2(const uint4* __restrict__ xn4,
                                                     const float* __restrict__ nrm,
                                                     const int4* __restrict__ meta,
                                                     const int* __restrict__ col,
                                                     const float* __restrict__ W2,
                                                     const float* __restrict__ b2,
                                                     float* __restrict__ out,
                                                     int N) {
    __shared__ __align__(16) float W2T[64 * 68];   // 17 KiB, [k][j] stride 68
    __shared__ __align__(16) float oL[16][68];     // 4.25 KiB
    const int tid  = threadIdx.x;
    const int lane = tid & 63;
    const int g    = (lane >> 3) & 1;
    const int sub  = lane & 7;
    const int q    = tid >> 4;         // quarter within block [0,16)
    const int il   = tid & 15;         // lane within quarter
    const int slot = blockIdx.x * 16 + q;
    const bool slotOK = slot < N;

    // stage W2^T: coalesced global read (r10 form)
    {
        const float4* src = (const float4*)W2;
#pragma unroll
        for (int i2 = 0; i2 < 4; ++i2) {
            int idx = tid + i2 * 256;            // [0,1024) float4 of 64x64
            int j = idx >> 4, k4 = idx & 15;
            float4 v = src[idx];
            W2T[(4 * k4 + 0) * 68 + j] = v.x;
            W2T[(4 * k4 + 1) * 68 + j] = v.y;
            W2T[(4 * k4 + 2) * 68 + j] = v.z;
            W2T[(4 * k4 + 3) * 68 + j] = v.w;
        }
    }

    int nid = 0;
    if (slotOK) {
        const int4 m0 = meta[slot];
        nid = m0.x;
        const int p0 = m0.y, p1 = m0.z;
        const int i = nid;

        U4H hi_;
        hi_.u = xn4[(unsigned)i * 8u + sub];
        {
            const _Float16 L2E = (_Float16)1.4426950408889634f;
            h2 l2 = {L2E, L2E};
#pragma unroll
            for (int c = 0; c < 4; ++c) hi_.h[c] *= l2;
        }

        const int mid = p0 + ((p1 - p0 + 1) >> 1);
        int       t   = g ? mid : p0;
        const int e_  = g ? p1  : mid;

        float den = 0.f;
        U4H acc;
        acc.h[0] = mkh2(0.f, 0.f); acc.h[1] = mkh2(0.f, 0.f);
        acc.h[2] = mkh2(0.f, 0.f); acc.h[3] = mkh2(0.f, 0.f);

        AGNN_EDGE_LOOP()

        den = dpp_addf<0x140>(den);
#pragma unroll
        for (int c = 0; c < 4; ++c) {
            UHI a; a.h = acc.h[c];
            UHI b; b.u = (unsigned)__shfl_xor((int)a.u, 8, 64);
            acc.h[c] = a.h + b.h;
        }

        const float id = 1.f / fmaxf(den, 1e-12f);
        float o[8];
#pragma unroll
        for (int c = 0; c < 4; ++c) {
            o[2 * c]     = fmaxf((float)acc.h[c].x * id, 0.f);
            o[2 * c + 1] = fmaxf((float)acc.h[c].y * id, 0.f);
        }

        // stage this node's f32 o into oL (no f16 rounding)
        if (g == 0) {
            oL[q][8 * sub + 0] = o[0];
            oL[q][8 * sub + 1] = o[1];
            oL[q][8 * sub + 2] = o[2];
            oL[q][8 * sub + 3] = o[3];
            oL[q][8 * sub + 4] = o[4];
            oL[q][8 * sub + 5] = o[5];
            oL[q][8 * sub + 6] = o[6];
            oL[q][8 * sub + 7] = o[7];
        }
    }

    __syncthreads();   // W2T + oL visible to all

    if (slotOK) {
        float4 res = ((const float4*)b2)[il];
#pragma unroll 4
        for (int kk = 0; kk < 16; ++kk) {
            const float4 o4 = *(const float4*)&oL[q][4 * kk];
#pragma unroll
            for (int c = 0; c < 4; ++c) {
                const int k = 4 * kk + c;
                const float4 w4 = *(const float4*)&W2T[k * 68 + 4 * il];
                const float ok = (c == 0) ? o4.x : (c == 1) ? o4.y
                               : (c == 2) ? o4.z : o4.w;
                res.x = fmaf(ok, w4.x, res.x);
                res.y = fmaf(ok, w4.y, res.y);
                res.z = fmaf(ok, w4.z, res.z);
                res.w = fmaf(ok, w4.w, res.w);
            }
        }
        *(float4*)&out[(size_t)nid * 64 + 4 * il] = res;
    }
}

extern "C" void kernel_launch(void* const* d_in, const int* in_sizes, int n_in,
                              void* d_out, int out_size, void* d_ws, size_t ws_size,
                              hipStream_t stream) {
    const float* x   = (const float*)d_in[0];
    const int*   row = (const int*)d_in[1];
    const int*   col = (const int*)d_in[2];
    const float* W1  = (const float*)d_in[3];
    const float* b1  = (const float*)d_in[4];
    const float* W2  = (const float*)d_in[5];
    const float* b2  = (const float*)d_in[6];
    float* out = (float*)d_out;

    const int N = in_sizes[0] / 128;
    const int E = in_sizes[1];

    char* ws = (char*)d_ws;
    size_t off = 0;
    unsigned short* ha = (unsigned short*)(ws + off); off += (size_t)N * 64 * 2;
    unsigned short* hb = (unsigned short*)(ws + off); off += (size_t)N * 64 * 2;
    float* na_  = (float*)(ws + off); off += (size_t)N * sizeof(float);
    float* nb_  = (float*)(ws + off); off += (size_t)N * sizeof(float);
    off = (off + 15) & ~(size_t)15;
    int4*  meta = (int4*) (ws + off); off += (size_t)N * sizeof(int4);
    (void)ws_size; (void)n_in; (void)out_size;

    // packed: sort blocks + gemm1 blocks, overlaid LDS (16.4 KB both paths)
    const int nbSort = (N + PSEG - 1) / PSEG;
    const int nbG    = (N + 63) / 64;
    pre_gemm1<<<nbSort + nbG, 256, 0, stream>>>(row, meta, x, W1, b1,
                                                ha, na_, N, E, nbSort);

    const int nb16 = (N + 15) / 16;
    unsigned short* hc = ha; unsigned short* hn = hb;
    float* nc = na_; float* nn = nb_;
    for (int l = 0; l < 3; ++l) {
        agnn_layer<<<nb16, 256, 0, stream>>>((const uint4*)hc, nc, meta, col,
                                             (uint4*)hn, nn, N);
        unsigned short* t = hc; hc = hn; hn = t;
        float* tf = nc; nc = nn; nn = tf;
    }

    // layer 4 + gemm2 fused
    agnn_gemm2<<<nb16, 256, 0, stream>>>((const uint4*)hc, nc, meta, col,
                                         W2, b2, out, N);
}